// Round 3
// baseline (167.184 us; speedup 1.0000x reference)
//
#include <hip/hip_runtime.h>

// Problem constants (B=1)
constexpr int DD = 8, HH = 24, WW = 24;
constexpr int NQ = DD * HH * WW;      // 4608 query positions
constexpr int CIN = 192;
constexpr int CQKV = 576;             // 3 scales * 192
constexpr float ATT_SCALE = 0.17677669529663687f;  // 32^-0.5
constexpr int NROW = DD * HH;         // 192 (d,h) rows

// ---------------------------------------------------------------------------
// GEMM with bias: C[M,N] = A[M,K] @ B[K,N] + bias[N]
// Round-1 version (measured faster than transposed-A variant: 83 vs 91 us).
// ---------------------------------------------------------------------------
__global__ __launch_bounds__(256)
void gemm_bias_kernel(const float* __restrict__ A, const float* __restrict__ B,
                      const float* __restrict__ bias, float* __restrict__ C,
                      int M, int N, int K)
{
    constexpr int BM = 64, BN = 64, BK = 32;
    __shared__ float As[BM][BK + 4];
    __shared__ float Bs[BK][BN];

    const int tid = threadIdx.x;
    const int tx = tid & 15;
    const int ty = tid >> 4;
    const int tx4 = tx * 4, ty4 = ty * 4;
    const int bm = blockIdx.x * BM;
    const int bn = blockIdx.y * BN;

    float acc[4][4] = {};

    for (int kk = 0; kk < K; kk += BK) {
        #pragma unroll
        for (int v = 0; v < BM * BK / 4; v += 256) {
            int idx = v + tid;
            int r = idx >> 3;
            int c = (idx & 7) << 2;
            *(float4*)(&As[r][c]) = *(const float4*)(A + (long)(bm + r) * K + kk + c);
        }
        #pragma unroll
        for (int v = 0; v < BK * BN / 4; v += 256) {
            int idx = v + tid;
            int r = idx >> 4;
            int c = (idx & 15) << 2;
            *(float4*)(&Bs[r][c]) = *(const float4*)(B + (long)(kk + r) * N + bn + c);
        }
        __syncthreads();
        #pragma unroll
        for (int k2 = 0; k2 < BK; ++k2) {
            float a0 = As[ty4 + 0][k2];
            float a1 = As[ty4 + 1][k2];
            float a2 = As[ty4 + 2][k2];
            float a3 = As[ty4 + 3][k2];
            float4 b = *(const float4*)(&Bs[k2][tx4]);
            acc[0][0] += a0 * b.x; acc[0][1] += a0 * b.y; acc[0][2] += a0 * b.z; acc[0][3] += a0 * b.w;
            acc[1][0] += a1 * b.x; acc[1][1] += a1 * b.y; acc[1][2] += a1 * b.z; acc[1][3] += a1 * b.w;
            acc[2][0] += a2 * b.x; acc[2][1] += a2 * b.y; acc[2][2] += a2 * b.z; acc[2][3] += a2 * b.w;
            acc[3][0] += a3 * b.x; acc[3][1] += a3 * b.y; acc[3][2] += a3 * b.z; acc[3][3] += a3 * b.w;
        }
        __syncthreads();
    }

    const float4 bv = *(const float4*)(bias + bn + tx4);
    #pragma unroll
    for (int i = 0; i < 4; ++i) {
        float4 o;
        o.x = acc[i][0] + bv.x;
        o.y = acc[i][1] + bv.y;
        o.z = acc[i][2] + bv.z;
        o.w = acc[i][3] + bv.w;
        *(float4*)(C + (long)(bm + ty4 + i) * N + bn + tx4) = o;
    }
}

// ---------------------------------------------------------------------------
// Shared attention building blocks
// Thread t (384/block): w = t>>4 (24), hd = (t>>3)&1, d4 = t&7 (dim quad).
// ---------------------------------------------------------------------------
constexpr int ROWF = 68;              // 64 ch + 4 pad
constexpr int ROWBUF = WW * ROWF;     // 1632 floats per buffer

// Partial-entry counts per scale: NROW * K * WW * 2
constexpr int EB0 = 0;
constexpr int EB1 = NROW * 3 * WW * 2;            // 27648
constexpr int EB2 = EB1 + NROW * 5 * WW * 2;      // 73728
constexpr int ETOT = EB2 + NROW * 7 * WW * 2;     // 138240

// ---------------------------------------------------------------------------
// Split kernel: one block per (scale, row, i). Does K j-iterations of
// (stage k/v row -> online softmax over K w-window). Writes m/l/acc partials.
// ---------------------------------------------------------------------------
template<int K>
__device__ __forceinline__
void split_row(const float* __restrict__ qkv,
               float* __restrict__ accs, float* __restrict__ stats,
               int r, int i, int scale, int ebase,
               int w, int hd, int d4, int tid,
               float* __restrict__ ksh, float* __restrict__ vsh)
{
    const int dq = r / HH, hq = r % HH;

    int sd = dq - K / 2; sd = sd < 0 ? 0 : (sd > DD - K ? DD - K : sd);
    int sh = hq - K / 2; sh = sh < 0 ? 0 : (sh > HH - K ? HH - K : sh);
    int sw = w  - K / 2; sw = sw < 0 ? 0 : (sw > WW - K ? WW - K : sw);

    const int q = (dq * HH + hq) * WW + w;

    float4 qv = *(const float4*)(qkv + (long)q * CQKV + scale * 192 + hd * 32 + d4 * 4);
    qv.x *= ATT_SCALE; qv.y *= ATT_SCALE; qv.z *= ATT_SCALE; qv.w *= ATT_SCALE;

    const int lwn = tid >> 4;
    const int lc  = (tid & 15) << 2;

    auto load_kv = [&](int buf, int j) {
        const float* p = qkv + (long)(((sd + i) * HH + (sh + j)) * WW + lwn) * CQKV
                       + scale * 192 + lc;
        float4 kk = *(const float4*)(p + 64);
        float4 vv = *(const float4*)(p + 128);
        *(float4*)(ksh + buf * ROWBUF + lwn * ROWF + lc) = kk;
        *(float4*)(vsh + buf * ROWBUF + lwn * ROWF + lc) = vv;
    };

    float m = -1e30f, sum = 0.f;
    float4 acc = make_float4(0.f, 0.f, 0.f, 0.f);
    const int choff = hd * 32 + d4 * 4;

    load_kv(0, 0);
    int buf = 0;

    for (int j = 0; j < K; ++j) {
        __syncthreads();
        if (j + 1 < K) load_kv(buf ^ 1, j + 1);

        const float* kb = ksh + buf * ROWBUF + choff;
        float lg[K];
        #pragma unroll
        for (int n = 0; n < K; ++n) {
            float4 kk = *(const float4*)(kb + (sw + n) * ROWF);
            float p = qv.x * kk.x + qv.y * kk.y + qv.z * kk.z + qv.w * kk.w;
            p += __shfl_xor(p, 1);
            p += __shfl_xor(p, 2);
            p += __shfl_xor(p, 4);
            lg[n] = p;
        }
        float mloc = lg[0];
        #pragma unroll
        for (int n = 1; n < K; ++n) mloc = fmaxf(mloc, lg[n]);
        float mnew = fmaxf(m, mloc);
        float alpha = __expf(m - mnew);
        m = mnew;
        sum *= alpha;
        acc.x *= alpha; acc.y *= alpha; acc.z *= alpha; acc.w *= alpha;

        const float* vb = vsh + buf * ROWBUF + choff;
        #pragma unroll
        for (int n = 0; n < K; ++n) {
            float pr = __expf(lg[n] - mnew);
            sum += pr;
            float4 vv = *(const float4*)(vb + (sw + n) * ROWF);
            acc.x += pr * vv.x;
            acc.y += pr * vv.y;
            acc.z += pr * vv.z;
            acc.w += pr * vv.w;
        }
        buf ^= 1;
    }

    const int e = ebase + ((r * K + i) * WW + w) * 2 + hd;
    if (d4 == 0) {
        stats[2 * e]     = m;
        stats[2 * e + 1] = sum;
    }
    *(float4*)(accs + (long)e * 32 + d4 * 4) = acc;
}

__global__ __launch_bounds__(384)
void na3d_split_kernel(const float* __restrict__ qkv,
                       float* __restrict__ accs, float* __restrict__ stats)
{
    __shared__ float ksh[2 * ROWBUF];
    __shared__ float vsh[2 * ROWBUF];

    const int tid = threadIdx.x;
    const int w  = tid >> 4;
    const int hd = (tid >> 3) & 1;
    const int d4 = tid & 7;

    // Longest-work blocks first: scale2 (K=7), then scale1 (K=5), then scale0.
    const int bid = blockIdx.x;            // 2880 total
    if (bid < NROW * 7) {
        int r = bid / 7, i = bid % 7;
        split_row<7>(qkv, accs, stats, r, i, 2, EB2, w, hd, d4, tid, ksh, vsh);
    } else if (bid < NROW * 7 + NROW * 5) {
        int t = bid - NROW * 7;
        int r = t / 5, i = t % 5;
        split_row<5>(qkv, accs, stats, r, i, 1, EB1, w, hd, d4, tid, ksh, vsh);
    } else {
        int t = bid - NROW * 7 - NROW * 5;
        int r = t / 3, i = t % 3;
        split_row<3>(qkv, accs, stats, r, i, 0, EB0, w, hd, d4, tid, ksh, vsh);
    }
}

// ---------------------------------------------------------------------------
// Combine: one thread per (scale, row, w, head, d4) = 221184 threads.
// Merges K partials per (q, scale, head), writes y.
// ---------------------------------------------------------------------------
__global__ __launch_bounds__(256)
void na3d_combine_kernel(const float* __restrict__ accs,
                         const float* __restrict__ stats,
                         float* __restrict__ y)
{
    const int n = blockIdx.x * 256 + threadIdx.x;     // < 221184
    constexpr int PER_SCALE = NROW * WW * 2 * 8;      // 73728 (mult of 256)
    const int scale = n / PER_SCALE;
    const int rem = n - scale * PER_SCALE;
    const int d4 = rem & 7;
    const int hd = (rem >> 3) & 1;
    const int t  = rem >> 4;                          // row*24 + w
    const int w  = t % WW;
    const int row = t / WW;

    const int K = scale == 0 ? 3 : (scale == 1 ? 5 : 7);
    const int ebase = scale == 0 ? EB0 : (scale == 1 ? EB1 : EB2);

    float mv[7], sv[7];
    float M = -1e30f;
    for (int i = 0; i < K; ++i) {
        int e = ebase + ((row * K + i) * WW + w) * 2 + hd;
        mv[i] = stats[2 * e];
        sv[i] = stats[2 * e + 1];
        M = fmaxf(M, mv[i]);
    }
    float S = 0.f;
    float4 o = make_float4(0.f, 0.f, 0.f, 0.f);
    for (int i = 0; i < K; ++i) {
        int e = ebase + ((row * K + i) * WW + w) * 2 + hd;
        float wgt = __expf(mv[i] - M);
        S += sv[i] * wgt;
        float4 a = *(const float4*)(accs + (long)e * 32 + d4 * 4);
        o.x += wgt * a.x; o.y += wgt * a.y; o.z += wgt * a.z; o.w += wgt * a.w;
    }
    const float rs = 1.0f / S;
    const int q = row * WW + w;
    float4 out;
    out.x = o.x * rs; out.y = o.y * rs; out.z = o.z * rs; out.w = o.w * rs;
    *(float4*)(y + (long)q * CIN + scale * 64 + hd * 32 + d4 * 4) = out;
}

// ---------------------------------------------------------------------------
// Fallback monolithic flash kernel (Round-2) if ws is too small for partials.
// ---------------------------------------------------------------------------
template<int K>
__device__ __forceinline__
void flash_row(const float* __restrict__ qkv, float* __restrict__ y,
               int dq, int hq, int scale,
               int w, int hd, int d4, int tid,
               float* __restrict__ ksh, float* __restrict__ vsh)
{
    constexpr int KK2 = K * K;

    int sd = dq - K / 2; sd = sd < 0 ? 0 : (sd > DD - K ? DD - K : sd);
    int sh = hq - K / 2; sh = sh < 0 ? 0 : (sh > HH - K ? HH - K : sh);
    int sw = w  - K / 2; sw = sw < 0 ? 0 : (sw > WW - K ? WW - K : sw);

    const int q = (dq * HH + hq) * WW + w;
    float4 qv = *(const float4*)(qkv + (long)q * CQKV + scale * 192 + hd * 32 + d4 * 4);
    qv.x *= ATT_SCALE; qv.y *= ATT_SCALE; qv.z *= ATT_SCALE; qv.w *= ATT_SCALE;

    const int lwn = tid >> 4;
    const int lc  = (tid & 15) << 2;

    auto load_kv = [&](int buf, int ij) {
        int i = ij / K, j = ij - (ij / K) * K;
        const float* p = qkv + (long)(((sd + i) * HH + (sh + j)) * WW + lwn) * CQKV
                       + scale * 192 + lc;
        float4 kk = *(const float4*)(p + 64);
        float4 vv = *(const float4*)(p + 128);
        *(float4*)(ksh + buf * ROWBUF + lwn * ROWF + lc) = kk;
        *(float4*)(vsh + buf * ROWBUF + lwn * ROWF + lc) = vv;
    };

    float m = -1e30f, sum = 0.f;
    float4 acc = make_float4(0.f, 0.f, 0.f, 0.f);
    const int choff = hd * 32 + d4 * 4;

    load_kv(0, 0);
    int buf = 0;

    for (int ij = 0; ij < KK2; ++ij) {
        __syncthreads();
        if (ij + 1 < KK2) load_kv(buf ^ 1, ij + 1);

        const float* kb = ksh + buf * ROWBUF + choff;
        float lg[K];
        #pragma unroll
        for (int n = 0; n < K; ++n) {
            float4 kk = *(const float4*)(kb + (sw + n) * ROWF);
            float p = qv.x * kk.x + qv.y * kk.y + qv.z * kk.z + qv.w * kk.w;
            p += __shfl_xor(p, 1);
            p += __shfl_xor(p, 2);
            p += __shfl_xor(p, 4);
            lg[n] = p;
        }
        float mloc = lg[0];
        #pragma unroll
        for (int n = 1; n < K; ++n) mloc = fmaxf(mloc, lg[n]);
        float mnew = fmaxf(m, mloc);
        float alpha = __expf(m - mnew);
        m = mnew;
        sum *= alpha;
        acc.x *= alpha; acc.y *= alpha; acc.z *= alpha; acc.w *= alpha;

        const float* vb = vsh + buf * ROWBUF + choff;
        #pragma unroll
        for (int n = 0; n < K; ++n) {
            float pr = __expf(lg[n] - mnew);
            sum += pr;
            float4 vv = *(const float4*)(vb + (sw + n) * ROWF);
            acc.x += pr * vv.x;
            acc.y += pr * vv.y;
            acc.z += pr * vv.z;
            acc.w += pr * vv.w;
        }
        buf ^= 1;
    }

    const float rs = 1.0f / sum;
    float4 o;
    o.x = acc.x * rs; o.y = acc.y * rs; o.z = acc.z * rs; o.w = acc.w * rs;
    *(float4*)(y + (long)q * CIN + scale * 64 + choff) = o;
}

__global__ __launch_bounds__(384)
void na3d_flash_kernel(const float* __restrict__ qkv, float* __restrict__ y)
{
    __shared__ float ksh[2 * ROWBUF];
    __shared__ float vsh[2 * ROWBUF];

    const int bid = blockIdx.x;
    const int scale = bid % 3;
    const int row = bid / 3;
    const int dq = row / HH, hq = row % HH;

    const int tid = threadIdx.x;
    const int w  = tid >> 4;
    const int hd = (tid >> 3) & 1;
    const int d4 = tid & 7;

    if (scale == 0)      flash_row<3>(qkv, y, dq, hq, 0, w, hd, d4, tid, ksh, vsh);
    else if (scale == 1) flash_row<5>(qkv, y, dq, hq, 1, w, hd, d4, tid, ksh, vsh);
    else                 flash_row<7>(qkv, y, dq, hq, 2, w, hd, d4, tid, ksh, vsh);
}

// ---------------------------------------------------------------------------
extern "C" void kernel_launch(void* const* d_in, const int* in_sizes, int n_in,
                              void* d_out, int out_size, void* d_ws, size_t ws_size,
                              hipStream_t stream)
{
    const float* x      = (const float*)d_in[0];
    const float* W_qkv  = (const float*)d_in[1];
    const float* b_qkv  = (const float*)d_in[2];
    const float* W_proj = (const float*)d_in[3];
    const float* b_proj = (const float*)d_in[4];
    float* out = (float*)d_out;

    float* qkv = (float*)d_ws;                       // 2,654,208 floats
    float* y   = qkv + (long)NQ * CQKV;              //   884,736 floats
    float* accs = y + (long)NQ * CIN;                // 4,423,680 floats
    float* stats = accs + (long)ETOT * 32;           //   276,480 floats
    const size_t need = ((long)NQ * CQKV + (long)NQ * CIN
                         + (long)ETOT * 32 + (long)ETOT * 2) * sizeof(float);

    gemm_bias_kernel<<<dim3(NQ / 64, CQKV / 64), 256, 0, stream>>>(x, W_qkv, b_qkv, qkv, NQ, CQKV, CIN);

    if (ws_size >= need) {
        na3d_split_kernel<<<dim3(NROW * (3 + 5 + 7)), 384, 0, stream>>>(qkv, accs, stats);
        na3d_combine_kernel<<<dim3(3 * NQ * 16 / 256), 256, 0, stream>>>(accs, stats, y);
    } else {
        na3d_flash_kernel<<<dim3(3 * NROW), 384, 0, stream>>>(qkv, y);
    }

    gemm_bias_kernel<<<dim3(NQ / 64, CIN / 64), 256, 0, stream>>>(y, W_proj, b_proj, out, NQ, CIN, CIN);
}

// Round 4
// 144.334 us; speedup vs baseline: 1.1583x; 1.1583x over previous
//
#include <hip/hip_runtime.h>

typedef unsigned short ushort_t;
typedef unsigned int uint_t;
typedef __attribute__((ext_vector_type(8))) short short8;
typedef __attribute__((ext_vector_type(4))) float f32x4;

// Problem constants (B=1)
constexpr int DD = 8, HH = 24, WW = 24;
constexpr int NQ = DD * HH * WW;      // 4608 query positions
constexpr int CIN = 192;
constexpr int CQKV = 576;             // 3 scales * 192
constexpr int KP = 576;               // bf16x3 expanded K' = 3*192
constexpr float ATT_SCALE = 0.17677669529663687f;  // 32^-0.5
constexpr int NROW = DD * HH;         // 192 (d,h) rows

// ---------------------------------------------------------------------------
// bf16 hi/lo split helpers (RNE)
// ---------------------------------------------------------------------------
__device__ __forceinline__ ushort_t bf16h(float x) {
    uint_t u = __float_as_uint(x);
    u += 0x7FFFu + ((u >> 16) & 1u);
    return (ushort_t)(u >> 16);
}
__device__ __forceinline__ float bf16f(ushort_t h) {
    return __uint_as_float(((uint_t)h) << 16);
}

// ---------------------------------------------------------------------------
// convert x (fp32 [M][192]) -> A' (bf16 [M][576] = [hi | lo | hi])
// one thread per (m, k-quad); 221184 threads
// ---------------------------------------------------------------------------
__global__ __launch_bounds__(256)
void convert_a_kernel(const float* __restrict__ X, ushort_t* __restrict__ Ab)
{
    const int idx = blockIdx.x * 256 + threadIdx.x;
    const int m = idx / 48;
    const int k0 = (idx - m * 48) * 4;
    float4 v = *(const float4*)(X + (long)m * CIN + k0);
    ushort4 hv, lv;
    hv.x = bf16h(v.x); lv.x = bf16h(v.x - bf16f(hv.x));
    hv.y = bf16h(v.y); lv.y = bf16h(v.y - bf16f(hv.y));
    hv.z = bf16h(v.z); lv.z = bf16h(v.z - bf16f(hv.z));
    hv.w = bf16h(v.w); lv.w = bf16h(v.w - bf16f(hv.w));
    ushort_t* row = Ab + (long)m * KP;
    *(ushort4*)(row + k0)           = hv;   // Ah
    *(ushort4*)(row + CIN + k0)     = lv;   // Al
    *(ushort4*)(row + 2 * CIN + k0) = hv;   // Ah
}

// ---------------------------------------------------------------------------
// convert W (fp32 [192][N]) -> B' (bf16 [N][576] = [hi ; hi ; lo] along k')
// one thread per (k, n-quad); K*N/4 threads (grid exact)
// ---------------------------------------------------------------------------
__global__ __launch_bounds__(256)
void convert_b_kernel(const float* __restrict__ W, ushort_t* __restrict__ Bb, int N)
{
    const int idx = blockIdx.x * 256 + threadIdx.x;
    const int nq = N / 4;
    const int k = idx / nq;
    const int n0 = (idx - k * nq) * 4;
    float4 v = *(const float4*)(W + (long)k * N + n0);
    float vv[4] = {v.x, v.y, v.z, v.w};
    #pragma unroll
    for (int c = 0; c < 4; ++c) {
        ushort_t hi = bf16h(vv[c]);
        ushort_t lo = bf16h(vv[c] - bf16f(hi));
        ushort_t* row = Bb + (long)(n0 + c) * KP;
        row[k]           = hi;   // pairs with Ah
        row[CIN + k]     = hi;   // pairs with Al
        row[2 * CIN + k] = lo;   // pairs with Ah
    }
}

// ---------------------------------------------------------------------------
// bf16x3 MFMA GEMM: C[M][N] fp32 = A'[M][576] x B'[N][576]^T + bias
// BM=BN=64, BK=64, 256 threads (4 waves in 2x2), 16x16x32 bf16 MFMA.
// As/Bs rows padded to 72 bf16 (16B-aligned, 2-way-max bank conflicts).
// ---------------------------------------------------------------------------
__global__ __launch_bounds__(256)
void gemm_mfma_kernel(const ushort_t* __restrict__ Ab, const ushort_t* __restrict__ Bb,
                      const float* __restrict__ bias, float* __restrict__ C, int N)
{
    __shared__ ushort_t As[64][72];
    __shared__ ushort_t Bs[64][72];

    const int tid = threadIdx.x;
    const int bm = blockIdx.x * 64;
    const int bn = blockIdx.y * 64;

    const int wv = tid >> 6;             // wave 0..3
    const int lane = tid & 63;
    const int lm = lane & 15;
    const int quad = lane >> 4;          // 0..3
    const int wr = (wv >> 1) * 32;       // wave row offset in tile
    const int wc = (wv & 1) * 32;        // wave col offset

    // staging indices: 2 x 16B chunks per thread per matrix
    const int r0 = tid >> 3;             // pass0 row (0..31)
    const int c0 = (tid & 7) * 8;        // bf16 col
    const int r1 = r0 + 32;              // pass1 row

    f32x4 acc[2][2] = {};

    for (int kk = 0; kk < KP; kk += 64) {
        // prefetch global (before barrier so latency overlaps previous compute)
        uint4 a0 = *(const uint4*)(Ab + (long)(bm + r0) * KP + kk + c0);
        uint4 a1 = *(const uint4*)(Ab + (long)(bm + r1) * KP + kk + c0);
        uint4 b0 = *(const uint4*)(Bb + (long)(bn + r0) * KP + kk + c0);
        uint4 b1 = *(const uint4*)(Bb + (long)(bn + r1) * KP + kk + c0);
        __syncthreads();
        *(uint4*)(&As[r0][c0]) = a0;
        *(uint4*)(&As[r1][c0]) = a1;
        *(uint4*)(&Bs[r0][c0]) = b0;
        *(uint4*)(&Bs[r1][c0]) = b1;
        __syncthreads();

        #pragma unroll
        for (int ks = 0; ks < 64; ks += 32) {
            short8 af0 = *(const short8*)(&As[wr + lm][ks + quad * 8]);
            short8 af1 = *(const short8*)(&As[wr + 16 + lm][ks + quad * 8]);
            short8 bf0 = *(const short8*)(&Bs[wc + lm][ks + quad * 8]);
            short8 bf1 = *(const short8*)(&Bs[wc + 16 + lm][ks + quad * 8]);
            acc[0][0] = __builtin_amdgcn_mfma_f32_16x16x32_bf16(af0, bf0, acc[0][0], 0, 0, 0);
            acc[0][1] = __builtin_amdgcn_mfma_f32_16x16x32_bf16(af0, bf1, acc[0][1], 0, 0, 0);
            acc[1][0] = __builtin_amdgcn_mfma_f32_16x16x32_bf16(af1, bf0, acc[1][0], 0, 0, 0);
            acc[1][1] = __builtin_amdgcn_mfma_f32_16x16x32_bf16(af1, bf1, acc[1][1], 0, 0, 0);
        }
    }

    // epilogue: C/D layout col=lane&15, row=quad*4+reg  [m89]
    #pragma unroll
    for (int tc = 0; tc < 2; ++tc) {
        const int n = bn + wc + tc * 16 + lm;
        const float bv = bias[n];
        #pragma unroll
        for (int tr = 0; tr < 2; ++tr) {
            const int mb = bm + wr + tr * 16 + quad * 4;
            #pragma unroll
            for (int reg = 0; reg < 4; ++reg)
                C[(long)(mb + reg) * N + n] = acc[tr][tc][reg] + bv;
        }
    }
}

// ---------------------------------------------------------------------------
// Attention split (chunked): one block per (scale, row, chunk-of-2-i).
// CK per scale = {2,3,4}; 1728 blocks total.
// Thread t (384): w = t>>4, hd = (t>>3)&1, d4 = t&7.
// ---------------------------------------------------------------------------
constexpr int ROWF = 68;
constexpr int ROWBUF = WW * ROWF;

constexpr int EB0 = 0;                         // scale0: CK=2 -> 18432 entries
constexpr int EB1 = NROW * 2 * WW * 2;         // 18432
constexpr int EB2 = EB1 + NROW * 3 * WW * 2;   // 46080
constexpr int ETOT = EB2 + NROW * 4 * WW * 2;  // 82944

template<int K>
__device__ __forceinline__
void split_chunk(const float* __restrict__ qkv,
                 float* __restrict__ accs, float* __restrict__ stats,
                 int r, int c, int nchunks, int scale, int ebase,
                 int w, int hd, int d4, int tid,
                 float* __restrict__ ksh, float* __restrict__ vsh)
{
    const int i0 = 2 * c;
    const int ni = (K - i0) < 2 ? (K - i0) : 2;
    const int NT = ni * K;

    const int dq = r / HH, hq = r % HH;
    int sd = dq - K / 2; sd = sd < 0 ? 0 : (sd > DD - K ? DD - K : sd);
    int sh = hq - K / 2; sh = sh < 0 ? 0 : (sh > HH - K ? HH - K : sh);
    int sw = w  - K / 2; sw = sw < 0 ? 0 : (sw > WW - K ? WW - K : sw);

    const int q = (dq * HH + hq) * WW + w;
    float4 qv = *(const float4*)(qkv + (long)q * CQKV + scale * 192 + hd * 32 + d4 * 4);
    qv.x *= ATT_SCALE; qv.y *= ATT_SCALE; qv.z *= ATT_SCALE; qv.w *= ATT_SCALE;

    const int lwn = tid >> 4;
    const int lc  = (tid & 15) << 2;

    auto load_kv = [&](int buf, int t) {
        int i = i0 + t / K;
        int j = t - (t / K) * K;
        const float* p = qkv + (long)(((sd + i) * HH + (sh + j)) * WW + lwn) * CQKV
                       + scale * 192 + lc;
        float4 kk = *(const float4*)(p + 64);
        float4 vv = *(const float4*)(p + 128);
        *(float4*)(ksh + buf * ROWBUF + lwn * ROWF + lc) = kk;
        *(float4*)(vsh + buf * ROWBUF + lwn * ROWF + lc) = vv;
    };

    float m = -1e30f, sum = 0.f;
    float4 acc = make_float4(0.f, 0.f, 0.f, 0.f);
    const int choff = hd * 32 + d4 * 4;

    load_kv(0, 0);
    int buf = 0;

    for (int t = 0; t < NT; ++t) {
        __syncthreads();
        if (t + 1 < NT) load_kv(buf ^ 1, t + 1);

        const float* kb = ksh + buf * ROWBUF + choff;
        float lg[K];
        #pragma unroll
        for (int n = 0; n < K; ++n) {
            float4 kk = *(const float4*)(kb + (sw + n) * ROWF);
            float p = qv.x * kk.x + qv.y * kk.y + qv.z * kk.z + qv.w * kk.w;
            p += __shfl_xor(p, 1);
            p += __shfl_xor(p, 2);
            p += __shfl_xor(p, 4);
            lg[n] = p;
        }
        float mloc = lg[0];
        #pragma unroll
        for (int n = 1; n < K; ++n) mloc = fmaxf(mloc, lg[n]);
        float mnew = fmaxf(m, mloc);
        float alpha = __expf(m - mnew);
        m = mnew;
        sum *= alpha;
        acc.x *= alpha; acc.y *= alpha; acc.z *= alpha; acc.w *= alpha;

        const float* vb = vsh + buf * ROWBUF + choff;
        #pragma unroll
        for (int n = 0; n < K; ++n) {
            float pr = __expf(lg[n] - mnew);
            sum += pr;
            float4 vv = *(const float4*)(vb + (sw + n) * ROWF);
            acc.x += pr * vv.x;
            acc.y += pr * vv.y;
            acc.z += pr * vv.z;
            acc.w += pr * vv.w;
        }
        buf ^= 1;
    }

    const int e = ebase + ((r * nchunks + c) * WW + w) * 2 + hd;
    if (d4 == 0) {
        stats[2 * e]     = m;
        stats[2 * e + 1] = sum;
    }
    *(float4*)(accs + (long)e * 32 + d4 * 4) = acc;
}

__global__ __launch_bounds__(384)
void na3d_split_kernel(const float* __restrict__ qkv,
                       float* __restrict__ accs, float* __restrict__ stats)
{
    __shared__ float ksh[2 * ROWBUF];
    __shared__ float vsh[2 * ROWBUF];

    const int tid = threadIdx.x;
    const int w  = tid >> 4;
    const int hd = (tid >> 3) & 1;
    const int d4 = tid & 7;

    const int bid = blockIdx.x;            // 1728 total; longest (K=7) first
    if (bid < NROW * 4) {
        int r = bid >> 2, c = bid & 3;
        split_chunk<7>(qkv, accs, stats, r, c, 4, 2, EB2, w, hd, d4, tid, ksh, vsh);
    } else if (bid < NROW * 4 + NROW * 3) {
        int t = bid - NROW * 4;
        int r = t / 3, c = t - (t / 3) * 3;
        split_chunk<5>(qkv, accs, stats, r, c, 3, 1, EB1, w, hd, d4, tid, ksh, vsh);
    } else {
        int t = bid - NROW * 7;
        int r = t >> 1, c = t & 1;
        split_chunk<3>(qkv, accs, stats, r, c, 2, 0, EB0, w, hd, d4, tid, ksh, vsh);
    }
}

// ---------------------------------------------------------------------------
// Combine: merge CK partials per (q, scale, head); write y directly in
// bf16x3 A'-layout ([hi | lo | hi], row stride 576) for the proj GEMM.
// one thread per (scale,row,w,hd,d4) = 221184
// ---------------------------------------------------------------------------
__global__ __launch_bounds__(256)
void na3d_combine_kernel(const float* __restrict__ accs,
                         const float* __restrict__ stats,
                         ushort_t* __restrict__ yb)
{
    const int n = blockIdx.x * 256 + threadIdx.x;
    constexpr int PER_SCALE = NROW * WW * 2 * 8;      // 73728
    const int scale = n / PER_SCALE;
    const int rem = n - scale * PER_SCALE;
    const int d4 = rem & 7;
    const int hd = (rem >> 3) & 1;
    const int t  = rem >> 4;
    const int w  = t % WW;
    const int row = t / WW;

    const int CK = scale == 0 ? 2 : (scale == 1 ? 3 : 4);
    const int ebase = scale == 0 ? EB0 : (scale == 1 ? EB1 : EB2);

    float mv[4], sv[4];
    float M = -1e30f;
    for (int c = 0; c < CK; ++c) {
        int e = ebase + ((row * CK + c) * WW + w) * 2 + hd;
        mv[c] = stats[2 * e];
        sv[c] = stats[2 * e + 1];
        M = fmaxf(M, mv[c]);
    }
    float S = 0.f;
    float4 o = make_float4(0.f, 0.f, 0.f, 0.f);
    for (int c = 0; c < CK; ++c) {
        int e = ebase + ((row * CK + c) * WW + w) * 2 + hd;
        float wgt = __expf(mv[c] - M);
        S += sv[c] * wgt;
        float4 a = *(const float4*)(accs + (long)e * 32 + d4 * 4);
        o.x += wgt * a.x; o.y += wgt * a.y; o.z += wgt * a.z; o.w += wgt * a.w;
    }
    const float rs = 1.0f / S;
    o.x *= rs; o.y *= rs; o.z *= rs; o.w *= rs;

    ushort4 hv, lv;
    hv.x = bf16h(o.x); lv.x = bf16h(o.x - bf16f(hv.x));
    hv.y = bf16h(o.y); lv.y = bf16h(o.y - bf16f(hv.y));
    hv.z = bf16h(o.z); lv.z = bf16h(o.z - bf16f(hv.z));
    hv.w = bf16h(o.w); lv.w = bf16h(o.w - bf16f(hv.w));

    const int q = row * WW + w;
    const int kp = scale * 64 + hd * 32 + d4 * 4;
    ushort_t* r0 = yb + (long)q * KP;
    *(ushort4*)(r0 + kp)           = hv;
    *(ushort4*)(r0 + CIN + kp)     = lv;
    *(ushort4*)(r0 + 2 * CIN + kp) = hv;
}

// ---------------------------------------------------------------------------
extern "C" void kernel_launch(void* const* d_in, const int* in_sizes, int n_in,
                              void* d_out, int out_size, void* d_ws, size_t ws_size,
                              hipStream_t stream)
{
    const float* x      = (const float*)d_in[0];
    const float* W_qkv  = (const float*)d_in[1];
    const float* b_qkv  = (const float*)d_in[2];
    const float* W_proj = (const float*)d_in[3];
    const float* b_proj = (const float*)d_in[4];
    float* out = (float*)d_out;

    // workspace layout (28.1 MB total; previous round proved ws >= 32.9 MB)
    float* qkv   = (float*)d_ws;                      // 2,654,208 fl
    float* accs  = qkv + (long)NQ * CQKV;             // 2,654,208 fl
    float* stats = accs + (long)ETOT * 32;            //   165,888 fl
    ushort_t* xyb = (ushort_t*)(stats + 2 * ETOT);    // 2,654,208 us (x' then y')
    ushort_t* Wbq = xyb + (long)NQ * KP;              //   331,776 us
    ushort_t* Wbp = Wbq + (long)CQKV * KP / 1;        // offset 576*576

    // 1) build bf16x3 operands
    convert_b_kernel<<<dim3(CIN * CQKV / 4 / 256), 256, 0, stream>>>(W_qkv, Wbq, CQKV);
    convert_b_kernel<<<dim3(CIN * CIN  / 4 / 256), 256, 0, stream>>>(W_proj, Wbp, CIN);
    convert_a_kernel<<<dim3(NQ * CIN / 4 / 256), 256, 0, stream>>>(x, xyb);

    // 2) qkv = x @ W_qkv + b_qkv   (MFMA bf16x3)
    gemm_mfma_kernel<<<dim3(NQ / 64, CQKV / 64), 256, 0, stream>>>(xyb, Wbq, b_qkv, qkv, CQKV);

    // 3) attention split + combine (combine emits y' in bf16x3)
    na3d_split_kernel<<<dim3(NROW * (4 + 3 + 2)), 384, 0, stream>>>(qkv, accs, stats);
    na3d_combine_kernel<<<dim3(3 * NQ * 16 / 256), 256, 0, stream>>>(accs, stats, xyb);

    // 4) out = y @ W_proj + b_proj   (MFMA bf16x3)
    gemm_mfma_kernel<<<dim3(NQ / 64, CIN / 64), 256, 0, stream>>>(xyb, Wbp, b_proj, out, CIN);
}

// Round 5
// 138.830 us; speedup vs baseline: 1.2042x; 1.0396x over previous
//
#include <hip/hip_runtime.h>

typedef unsigned short ushort_t;
typedef unsigned int uint_t;
typedef __attribute__((ext_vector_type(8))) short short8;
typedef __attribute__((ext_vector_type(4))) float f32x4;

// Problem constants (B=1)
constexpr int DD = 8, HH = 24, WW = 24;
constexpr int NQ = DD * HH * WW;      // 4608 query positions
constexpr int CIN = 192;
constexpr int CQKV = 576;             // 3 scales * 192
constexpr int KP = 576;               // bf16x3 expanded K' = 3*192
constexpr float ATT_SCALE = 0.17677669529663687f;  // 32^-0.5
constexpr int NROW = DD * HH;         // 192 (d,h) rows

// ---------------------------------------------------------------------------
// bf16 helpers (RNE)
// ---------------------------------------------------------------------------
__device__ __forceinline__ ushort_t bf16h(float x) {
    uint_t u = __float_as_uint(x);
    u += 0x7FFFu + ((u >> 16) & 1u);
    return (ushort_t)(u >> 16);
}
__device__ __forceinline__ float bf16f(ushort_t h) {
    return __uint_as_float(((uint_t)h) << 16);
}

// ---------------------------------------------------------------------------
// convert x (fp32 [M][192]) -> A' (bf16 [M][576] = [hi | lo | hi])
// ---------------------------------------------------------------------------
__global__ __launch_bounds__(256)
void convert_a_kernel(const float* __restrict__ X, ushort_t* __restrict__ Ab)
{
    const int idx = blockIdx.x * 256 + threadIdx.x;
    const int m = idx / 48;
    const int k0 = (idx - m * 48) * 4;
    float4 v = *(const float4*)(X + (long)m * CIN + k0);
    ushort4 hv, lv;
    hv.x = bf16h(v.x); lv.x = bf16h(v.x - bf16f(hv.x));
    hv.y = bf16h(v.y); lv.y = bf16h(v.y - bf16f(hv.y));
    hv.z = bf16h(v.z); lv.z = bf16h(v.z - bf16f(hv.z));
    hv.w = bf16h(v.w); lv.w = bf16h(v.w - bf16f(hv.w));
    ushort_t* row = Ab + (long)m * KP;
    *(ushort4*)(row + k0)           = hv;   // Ah
    *(ushort4*)(row + CIN + k0)     = lv;   // Al
    *(ushort4*)(row + 2 * CIN + k0) = hv;   // Ah
}

// ---------------------------------------------------------------------------
// Fused weight convert: W (fp32 [192][N]) -> B' (bf16 [N][576] = [hi|hi|lo])
// 32x32-tile LDS transpose: coalesced reads AND coalesced-ish writes.
// blocks 0..107 -> W_qkv (6 k-tiles x 18 n-tiles); 108..143 -> W_proj (6x6).
// ---------------------------------------------------------------------------
__global__ __launch_bounds__(256)
void convert_w_kernel(const float* __restrict__ Wq, const float* __restrict__ Wp,
                      ushort_t* __restrict__ Bq, ushort_t* __restrict__ Bp)
{
    __shared__ float T[32][36];
    int b = blockIdx.x;
    const float* W; ushort_t* Bb; int N;
    int kt, nt;
    if (b < 108) { W = Wq; Bb = Bq; N = CQKV; kt = b % 6; nt = b / 6; }
    else         { b -= 108; W = Wp; Bb = Bp; N = CIN; kt = b % 6; nt = b / 6; }
    const int k0 = kt * 32, n0 = nt * 32;
    const int tid = threadIdx.x;

    #pragma unroll
    for (int p = 0; p < 4; ++p) {
        int e = p * 256 + tid;
        int r = e >> 5, c = e & 31;
        T[c][r] = W[(long)(k0 + r) * N + n0 + c];   // coalesced read, transposed store
    }
    __syncthreads();
    // one (n, k-quad) per thread: 32 n-rows x 8 quads = 256
    const int n = tid >> 3;
    const int k4 = (tid & 7) * 4;
    float4 v = *(const float4*)(&T[n][k4]);
    ushort4 hv, lv;
    hv.x = bf16h(v.x); lv.x = bf16h(v.x - bf16f(hv.x));
    hv.y = bf16h(v.y); lv.y = bf16h(v.y - bf16f(hv.y));
    hv.z = bf16h(v.z); lv.z = bf16h(v.z - bf16f(hv.z));
    hv.w = bf16h(v.w); lv.w = bf16h(v.w - bf16f(hv.w));
    ushort_t* row = Bb + (long)(n0 + n) * KP + k0 + k4;
    *(ushort4*)(row)           = hv;   // pairs Ah
    *(ushort4*)(row + CIN)     = hv;   // pairs Al
    *(ushort4*)(row + 2 * CIN) = lv;   // pairs Ah
}

// ---------------------------------------------------------------------------
// bf16x3 MFMA GEMM: C[M][N] = A'[M][576] x B'[N][576]^T + bias
// BM=BN=64, BK=64, 256 threads (4 waves 2x2), 16x16x32 bf16 MFMA.
// Epilogue bounces C through LDS for coalesced global stores; BF16OUT selects
// bf16 output (qkv) vs fp32 output (final out).
// ---------------------------------------------------------------------------
template<bool BF16OUT>
__global__ __launch_bounds__(256)
void gemm_mfma_kernel(const ushort_t* __restrict__ Ab, const ushort_t* __restrict__ Bb,
                      const float* __restrict__ bias, void* __restrict__ Cout, int N)
{
    __shared__ ushort_t As[64][72];
    __shared__ ushort_t Bs[64][72];
    __shared__ float Ct[64][68];

    const int tid = threadIdx.x;
    const int bm = blockIdx.x * 64;
    const int bn = blockIdx.y * 64;

    const int wv = tid >> 6;
    const int lane = tid & 63;
    const int lm = lane & 15;
    const int quad = lane >> 4;
    const int wr = (wv >> 1) * 32;
    const int wc = (wv & 1) * 32;

    const int r0 = tid >> 3;
    const int c0 = (tid & 7) * 8;
    const int r1 = r0 + 32;

    f32x4 acc[2][2] = {};

    for (int kk = 0; kk < KP; kk += 64) {
        uint4 a0 = *(const uint4*)(Ab + (long)(bm + r0) * KP + kk + c0);
        uint4 a1 = *(const uint4*)(Ab + (long)(bm + r1) * KP + kk + c0);
        uint4 b0 = *(const uint4*)(Bb + (long)(bn + r0) * KP + kk + c0);
        uint4 b1 = *(const uint4*)(Bb + (long)(bn + r1) * KP + kk + c0);
        __syncthreads();
        *(uint4*)(&As[r0][c0]) = a0;
        *(uint4*)(&As[r1][c0]) = a1;
        *(uint4*)(&Bs[r0][c0]) = b0;
        *(uint4*)(&Bs[r1][c0]) = b1;
        __syncthreads();

        #pragma unroll
        for (int ks = 0; ks < 64; ks += 32) {
            short8 af0 = *(const short8*)(&As[wr + lm][ks + quad * 8]);
            short8 af1 = *(const short8*)(&As[wr + 16 + lm][ks + quad * 8]);
            short8 bf0 = *(const short8*)(&Bs[wc + lm][ks + quad * 8]);
            short8 bf1 = *(const short8*)(&Bs[wc + 16 + lm][ks + quad * 8]);
            acc[0][0] = __builtin_amdgcn_mfma_f32_16x16x32_bf16(af0, bf0, acc[0][0], 0, 0, 0);
            acc[0][1] = __builtin_amdgcn_mfma_f32_16x16x32_bf16(af0, bf1, acc[0][1], 0, 0, 0);
            acc[1][0] = __builtin_amdgcn_mfma_f32_16x16x32_bf16(af1, bf0, acc[1][0], 0, 0, 0);
            acc[1][1] = __builtin_amdgcn_mfma_f32_16x16x32_bf16(af1, bf1, acc[1][1], 0, 0, 0);
        }
    }

    // epilogue: C/D layout col=lane&15, row=quad*4+reg  [m89] -> LDS bounce
    #pragma unroll
    for (int tc = 0; tc < 2; ++tc) {
        const float bv = bias[bn + wc + tc * 16 + lm];
        #pragma unroll
        for (int tr = 0; tr < 2; ++tr) {
            #pragma unroll
            for (int reg = 0; reg < 4; ++reg)
                Ct[wr + tr * 16 + quad * 4 + reg][wc + tc * 16 + lm] = acc[tr][tc][reg] + bv;
        }
    }
    __syncthreads();
    // coalesced readout: 4 passes of 16 rows x 64 cols
    const int orow = tid >> 4;
    const int oc4 = (tid & 15) * 4;
    #pragma unroll
    for (int p = 0; p < 4; ++p) {
        const int r = orow + p * 16;
        float4 v = *(const float4*)(&Ct[r][oc4]);
        if (BF16OUT) {
            ushort4 hv;
            hv.x = bf16h(v.x); hv.y = bf16h(v.y); hv.z = bf16h(v.z); hv.w = bf16h(v.w);
            *(ushort4*)((ushort_t*)Cout + (long)(bm + r) * N + bn + oc4) = hv;
        } else {
            *(float4*)((float*)Cout + (long)(bm + r) * N + bn + oc4) = v;
        }
    }
}

// ---------------------------------------------------------------------------
// Attention split (chunked), qkv in bf16. Staging converts to fp32 in LDS;
// core loop identical to Round-4.
// ---------------------------------------------------------------------------
constexpr int ROWF = 68;
constexpr int ROWBUF = WW * ROWF;

constexpr int EB0 = 0;
constexpr int EB1 = NROW * 2 * WW * 2;         // 18432
constexpr int EB2 = EB1 + NROW * 3 * WW * 2;   // 46080
constexpr int ETOT = EB2 + NROW * 4 * WW * 2;  // 82944

template<int K>
__device__ __forceinline__
void split_chunk(const ushort_t* __restrict__ qkv,
                 float* __restrict__ accs, float* __restrict__ stats,
                 int r, int c, int nchunks, int scale, int ebase,
                 int w, int hd, int d4, int tid,
                 float* __restrict__ ksh, float* __restrict__ vsh)
{
    const int i0 = 2 * c;
    const int ni = (K - i0) < 2 ? (K - i0) : 2;
    const int NT = ni * K;

    const int dq = r / HH, hq = r % HH;
    int sd = dq - K / 2; sd = sd < 0 ? 0 : (sd > DD - K ? DD - K : sd);
    int sh = hq - K / 2; sh = sh < 0 ? 0 : (sh > HH - K ? HH - K : sh);
    int sw = w  - K / 2; sw = sw < 0 ? 0 : (sw > WW - K ? WW - K : sw);

    const int q = (dq * HH + hq) * WW + w;
    ushort4 qu = *(const ushort4*)(qkv + (long)q * CQKV + scale * 192 + hd * 32 + d4 * 4);
    float4 qv;
    qv.x = bf16f(qu.x) * ATT_SCALE;
    qv.y = bf16f(qu.y) * ATT_SCALE;
    qv.z = bf16f(qu.z) * ATT_SCALE;
    qv.w = bf16f(qu.w) * ATT_SCALE;

    const int lwn = tid >> 4;
    const int lc  = (tid & 15) << 2;

    auto load_kv = [&](int buf, int t) {
        int i = i0 + t / K;
        int j = t - (t / K) * K;
        const ushort_t* p = qkv + (long)(((sd + i) * HH + (sh + j)) * WW + lwn) * CQKV
                          + scale * 192 + lc;
        ushort4 ku = *(const ushort4*)(p + 64);
        ushort4 vu = *(const ushort4*)(p + 128);
        float4 kk, vv;
        kk.x = bf16f(ku.x); kk.y = bf16f(ku.y); kk.z = bf16f(ku.z); kk.w = bf16f(ku.w);
        vv.x = bf16f(vu.x); vv.y = bf16f(vu.y); vv.z = bf16f(vu.z); vv.w = bf16f(vu.w);
        *(float4*)(ksh + buf * ROWBUF + lwn * ROWF + lc) = kk;
        *(float4*)(vsh + buf * ROWBUF + lwn * ROWF + lc) = vv;
    };

    float m = -1e30f, sum = 0.f;
    float4 acc = make_float4(0.f, 0.f, 0.f, 0.f);
    const int choff = hd * 32 + d4 * 4;

    load_kv(0, 0);
    int buf = 0;

    for (int t = 0; t < NT; ++t) {
        __syncthreads();
        if (t + 1 < NT) load_kv(buf ^ 1, t + 1);

        const float* kb = ksh + buf * ROWBUF + choff;
        float lg[K];
        #pragma unroll
        for (int n = 0; n < K; ++n) {
            float4 kk = *(const float4*)(kb + (sw + n) * ROWF);
            float p = qv.x * kk.x + qv.y * kk.y + qv.z * kk.z + qv.w * kk.w;
            p += __shfl_xor(p, 1);
            p += __shfl_xor(p, 2);
            p += __shfl_xor(p, 4);
            lg[n] = p;
        }
        float mloc = lg[0];
        #pragma unroll
        for (int n = 1; n < K; ++n) mloc = fmaxf(mloc, lg[n]);
        float mnew = fmaxf(m, mloc);
        float alpha = __expf(m - mnew);
        m = mnew;
        sum *= alpha;
        acc.x *= alpha; acc.y *= alpha; acc.z *= alpha; acc.w *= alpha;

        const float* vb = vsh + buf * ROWBUF + choff;
        #pragma unroll
        for (int n = 0; n < K; ++n) {
            float pr = __expf(lg[n] - mnew);
            sum += pr;
            float4 vv = *(const float4*)(vb + (sw + n) * ROWF);
            acc.x += pr * vv.x;
            acc.y += pr * vv.y;
            acc.z += pr * vv.z;
            acc.w += pr * vv.w;
        }
        buf ^= 1;
    }

    const int e = ebase + ((r * nchunks + c) * WW + w) * 2 + hd;
    if (d4 == 0) {
        stats[2 * e]     = m;
        stats[2 * e + 1] = sum;
    }
    *(float4*)(accs + (long)e * 32 + d4 * 4) = acc;
}

__global__ __launch_bounds__(384)
void na3d_split_kernel(const ushort_t* __restrict__ qkv,
                       float* __restrict__ accs, float* __restrict__ stats)
{
    __shared__ float ksh[2 * ROWBUF];
    __shared__ float vsh[2 * ROWBUF];

    const int tid = threadIdx.x;
    const int w  = tid >> 4;
    const int hd = (tid >> 3) & 1;
    const int d4 = tid & 7;

    const int bid = blockIdx.x;            // 1728 total; longest (K=7) first
    if (bid < NROW * 4) {
        int r = bid >> 2, c = bid & 3;
        split_chunk<7>(qkv, accs, stats, r, c, 4, 2, EB2, w, hd, d4, tid, ksh, vsh);
    } else if (bid < NROW * 4 + NROW * 3) {
        int t = bid - NROW * 4;
        int r = t / 3, c = t - (t / 3) * 3;
        split_chunk<5>(qkv, accs, stats, r, c, 3, 1, EB1, w, hd, d4, tid, ksh, vsh);
    } else {
        int t = bid - NROW * 7;
        int r = t >> 1, c = t & 1;
        split_chunk<3>(qkv, accs, stats, r, c, 2, 0, EB0, w, hd, d4, tid, ksh, vsh);
    }
}

// ---------------------------------------------------------------------------
// Combine: merge CK partials per (q, scale, head); write y in bf16x3
// A'-layout for the proj GEMM.
// ---------------------------------------------------------------------------
__global__ __launch_bounds__(256)
void na3d_combine_kernel(const float* __restrict__ accs,
                         const float* __restrict__ stats,
                         ushort_t* __restrict__ yb)
{
    const int n = blockIdx.x * 256 + threadIdx.x;
    constexpr int PER_SCALE = NROW * WW * 2 * 8;      // 73728
    const int scale = n / PER_SCALE;
    const int rem = n - scale * PER_SCALE;
    const int d4 = rem & 7;
    const int hd = (rem >> 3) & 1;
    const int t  = rem >> 4;
    const int w  = t % WW;
    const int row = t / WW;

    const int CK = scale == 0 ? 2 : (scale == 1 ? 3 : 4);
    const int ebase = scale == 0 ? EB0 : (scale == 1 ? EB1 : EB2);

    float mv[4], sv[4];
    float M = -1e30f;
    for (int c = 0; c < CK; ++c) {
        int e = ebase + ((row * CK + c) * WW + w) * 2 + hd;
        mv[c] = stats[2 * e];
        sv[c] = stats[2 * e + 1];
        M = fmaxf(M, mv[c]);
    }
    float S = 0.f;
    float4 o = make_float4(0.f, 0.f, 0.f, 0.f);
    for (int c = 0; c < CK; ++c) {
        int e = ebase + ((row * CK + c) * WW + w) * 2 + hd;
        float wgt = __expf(mv[c] - M);
        S += sv[c] * wgt;
        float4 a = *(const float4*)(accs + (long)e * 32 + d4 * 4);
        o.x += wgt * a.x; o.y += wgt * a.y; o.z += wgt * a.z; o.w += wgt * a.w;
    }
    const float rs = 1.0f / S;
    o.x *= rs; o.y *= rs; o.z *= rs; o.w *= rs;

    ushort4 hv, lv;
    hv.x = bf16h(o.x); lv.x = bf16h(o.x - bf16f(hv.x));
    hv.y = bf16h(o.y); lv.y = bf16h(o.y - bf16f(hv.y));
    hv.z = bf16h(o.z); lv.z = bf16h(o.z - bf16f(hv.z));
    hv.w = bf16h(o.w); lv.w = bf16h(o.w - bf16f(hv.w));

    const int q = row * WW + w;
    const int kp = scale * 64 + hd * 32 + d4 * 4;
    ushort_t* r0 = yb + (long)q * KP;
    *(ushort4*)(r0 + kp)           = hv;
    *(ushort4*)(r0 + CIN + kp)     = lv;
    *(ushort4*)(r0 + 2 * CIN + kp) = hv;
}

// ---------------------------------------------------------------------------
extern "C" void kernel_launch(void* const* d_in, const int* in_sizes, int n_in,
                              void* d_out, int out_size, void* d_ws, size_t ws_size,
                              hipStream_t stream)
{
    const float* x      = (const float*)d_in[0];
    const float* W_qkv  = (const float*)d_in[1];
    const float* b_qkv  = (const float*)d_in[2];
    const float* W_proj = (const float*)d_in[3];
    const float* b_proj = (const float*)d_in[4];
    float* out = (float*)d_out;

    // workspace layout (~22.5 MB; ws >= 28.1 MB proven in Round 4)
    float* accs   = (float*)d_ws;                          // 2,654,208 fl
    float* stats  = accs + (long)ETOT * 32;                //   165,888 fl
    ushort_t* qkvb = (ushort_t*)(stats + 2 * ETOT);        // 2,654,208 us
    ushort_t* xyb  = qkvb + (long)NQ * CQKV;               // 2,654,208 us
    ushort_t* Wbq  = xyb + (long)NQ * KP;                  //   331,776 us
    ushort_t* Wbp  = Wbq + (long)CQKV * KP;                //   110,592 us

    // 1) operand conversion (fused weights kernel + x)
    convert_w_kernel<<<dim3(144), 256, 0, stream>>>(W_qkv, W_proj, Wbq, Wbp);
    convert_a_kernel<<<dim3(NQ * CIN / 4 / 256), 256, 0, stream>>>(x, xyb);

    // 2) qkv = x @ W_qkv + b_qkv  -> bf16
    gemm_mfma_kernel<true><<<dim3(NQ / 64, CQKV / 64), 256, 0, stream>>>(xyb, Wbq, b_qkv, qkvb, CQKV);

    // 3) attention split + combine (combine overwrites xyb with y' bf16x3)
    na3d_split_kernel<<<dim3(NROW * (4 + 3 + 2)), 384, 0, stream>>>(qkvb, accs, stats);
    na3d_combine_kernel<<<dim3(3 * NQ * 16 / 256), 256, 0, stream>>>(accs, stats, xyb);

    // 4) out = y @ W_proj + b_proj  -> fp32
    gemm_mfma_kernel<false><<<dim3(NQ / 64, CIN / 64), 256, 0, stream>>>(xyb, Wbp, b_proj, out, CIN);
}

// Round 7
// 122.685 us; speedup vs baseline: 1.3627x; 1.1316x over previous
//
#include <hip/hip_runtime.h>

typedef unsigned short ushort_t;
typedef unsigned int uint_t;
typedef __attribute__((ext_vector_type(8))) short short8;
typedef __attribute__((ext_vector_type(4))) float f32x4;

// Problem constants (B=1)
constexpr int DD = 8, HH = 24, WW = 24;
constexpr int NQ = DD * HH * WW;      // 4608 query positions
constexpr int CIN = 192;
constexpr int CQKV = 576;             // 3 scales * 192
constexpr int KP = 576;               // bf16x3 expanded K' = 3*192
constexpr float ATT_SCALE = 0.17677669529663687f;  // 32^-0.5
constexpr int NROW = DD * HH;         // 192 (d,h) rows

// ---------------------------------------------------------------------------
// bf16 helpers (RNE)
// ---------------------------------------------------------------------------
__device__ __forceinline__ ushort_t bf16h(float x) {
    uint_t u = __float_as_uint(x);
    u += 0x7FFFu + ((u >> 16) & 1u);
    return (ushort_t)(u >> 16);
}
__device__ __forceinline__ float bf16f(ushort_t h) {
    return __uint_as_float(((uint_t)h) << 16);
}
// unpack 8 packed bf16 (as uint4) -> 8 fp32, exact (shift/mask only)
__device__ __forceinline__ void unpack8(uint4 u, float* f) {
    f[0] = __uint_as_float(u.x << 16); f[1] = __uint_as_float(u.x & 0xffff0000u);
    f[2] = __uint_as_float(u.y << 16); f[3] = __uint_as_float(u.y & 0xffff0000u);
    f[4] = __uint_as_float(u.z << 16); f[5] = __uint_as_float(u.z & 0xffff0000u);
    f[6] = __uint_as_float(u.w << 16); f[7] = __uint_as_float(u.w & 0xffff0000u);
}

// ---------------------------------------------------------------------------
// Fused weight convert: W (fp32 [192][N]) -> B' (bf16 [N][576] = [hi|hi|lo])
// blocks 0..107 -> W_qkv; 108..143 -> W_proj.
// ---------------------------------------------------------------------------
__global__ __launch_bounds__(256)
void convert_w_kernel(const float* __restrict__ Wq, const float* __restrict__ Wp,
                      ushort_t* __restrict__ Bq, ushort_t* __restrict__ Bp)
{
    __shared__ float T[32][36];
    int b = blockIdx.x;
    const float* W; ushort_t* Bb; int N;
    int kt, nt;
    if (b < 108) { W = Wq; Bb = Bq; N = CQKV; kt = b % 6; nt = b / 6; }
    else         { b -= 108; W = Wp; Bb = Bp; N = CIN; kt = b % 6; nt = b / 6; }
    const int k0 = kt * 32, n0 = nt * 32;
    const int tid = threadIdx.x;

    #pragma unroll
    for (int p = 0; p < 4; ++p) {
        int e = p * 256 + tid;
        int r = e >> 5, c = e & 31;
        T[c][r] = W[(long)(k0 + r) * N + n0 + c];
    }
    __syncthreads();
    const int n = tid >> 3;
    const int k4 = (tid & 7) * 4;
    float4 v = *(const float4*)(&T[n][k4]);
    ushort4 hv, lv;
    hv.x = bf16h(v.x); lv.x = bf16h(v.x - bf16f(hv.x));
    hv.y = bf16h(v.y); lv.y = bf16h(v.y - bf16f(hv.y));
    hv.z = bf16h(v.z); lv.z = bf16h(v.z - bf16f(hv.z));
    hv.w = bf16h(v.w); lv.w = bf16h(v.w - bf16f(hv.w));
    ushort_t* row = Bb + (long)(n0 + n) * KP + k0 + k4;
    *(ushort4*)(row)           = hv;   // pairs Ah
    *(ushort4*)(row + CIN)     = hv;   // pairs Al
    *(ushort4*)(row + 2 * CIN) = lv;   // pairs Ah
}

// ---------------------------------------------------------------------------
// bf16x3 MFMA GEMM, fp32 A consumed directly (hi/lo conversion in staging):
//   C[M][N] = A[M][192] (x3 expansion) x B'[N][576]^T + bias
// BM=BN=64, BK=64, 256 threads (4 waves 2x2), 16x16x32 bf16 MFMA.
// Phase p3 = kk/192: 0,2 -> hi(A), 1 -> lo(A); B' rows pre-built to match.
// ---------------------------------------------------------------------------
template<bool BF16OUT>
__global__ __launch_bounds__(256)
void gemm_mfma_kernel(const float* __restrict__ A, const ushort_t* __restrict__ Bb,
                      const float* __restrict__ bias, void* __restrict__ Cout, int N)
{
    __shared__ ushort_t As[64][72];
    __shared__ ushort_t Bs[64][72];
    __shared__ float Ct[64][68];

    const int tid = threadIdx.x;
    const int bm = blockIdx.x * 64;
    const int bn = blockIdx.y * 64;

    const int wv = tid >> 6;
    const int lane = tid & 63;
    const int lm = lane & 15;
    const int quad = lane >> 4;
    const int wr = (wv >> 1) * 32;
    const int wc = (wv & 1) * 32;

    // A staging: 4 passes of (row, float-quad)
    const int ar = tid >> 4;             // +16 per pass
    const int ac4 = (tid & 15) * 4;
    // B staging: 2 uint4 per thread
    const int br0 = tid >> 3;
    const int bc0 = (tid & 7) * 8;

    f32x4 acc[2][2] = {};

    for (int kk = 0; kk < KP; kk += 64) {
        const int p3 = kk / 192;
        const int k0 = kk - p3 * 192;
        // prefetch (before barrier: overlaps previous MFMA burst)
        float4 av[4];
        #pragma unroll
        for (int p = 0; p < 4; ++p)
            av[p] = *(const float4*)(A + (long)(bm + ar + p * 16) * CIN + k0 + ac4);
        uint4 b0 = *(const uint4*)(Bb + (long)(bn + br0) * KP + kk + bc0);
        uint4 b1 = *(const uint4*)(Bb + (long)(bn + br0 + 32) * KP + kk + bc0);
        __syncthreads();
        #pragma unroll
        for (int p = 0; p < 4; ++p) {
            float4 v = av[p];
            ushort4 hv;
            hv.x = bf16h(v.x); hv.y = bf16h(v.y); hv.z = bf16h(v.z); hv.w = bf16h(v.w);
            if (p3 == 1) {   // lo phase
                hv.x = bf16h(v.x - bf16f(hv.x));
                hv.y = bf16h(v.y - bf16f(hv.y));
                hv.z = bf16h(v.z - bf16f(hv.z));
                hv.w = bf16h(v.w - bf16f(hv.w));
            }
            *(ushort4*)(&As[ar + p * 16][ac4]) = hv;
        }
        *(uint4*)(&Bs[br0][bc0]) = b0;
        *(uint4*)(&Bs[br0 + 32][bc0]) = b1;
        __syncthreads();

        #pragma unroll
        for (int ks = 0; ks < 64; ks += 32) {
            short8 af0 = *(const short8*)(&As[wr + lm][ks + quad * 8]);
            short8 af1 = *(const short8*)(&As[wr + 16 + lm][ks + quad * 8]);
            short8 bf0 = *(const short8*)(&Bs[wc + lm][ks + quad * 8]);
            short8 bf1 = *(const short8*)(&Bs[wc + 16 + lm][ks + quad * 8]);
            acc[0][0] = __builtin_amdgcn_mfma_f32_16x16x32_bf16(af0, bf0, acc[0][0], 0, 0, 0);
            acc[0][1] = __builtin_amdgcn_mfma_f32_16x16x32_bf16(af0, bf1, acc[0][1], 0, 0, 0);
            acc[1][0] = __builtin_amdgcn_mfma_f32_16x16x32_bf16(af1, bf0, acc[1][0], 0, 0, 0);
            acc[1][1] = __builtin_amdgcn_mfma_f32_16x16x32_bf16(af1, bf1, acc[1][1], 0, 0, 0);
        }
    }

    // epilogue: C/D layout col=lane&15, row=quad*4+reg [m89] -> LDS bounce
    #pragma unroll
    for (int tc = 0; tc < 2; ++tc) {
        const float bv = bias[bn + wc + tc * 16 + lm];
        #pragma unroll
        for (int tr = 0; tr < 2; ++tr) {
            #pragma unroll
            for (int reg = 0; reg < 4; ++reg)
                Ct[wr + tr * 16 + quad * 4 + reg][wc + tc * 16 + lm] = acc[tr][tc][reg] + bv;
        }
    }
    __syncthreads();
    const int orow = tid >> 4;
    const int oc4 = (tid & 15) * 4;
    #pragma unroll
    for (int p = 0; p < 4; ++p) {
        const int r = orow + p * 16;
        float4 v = *(const float4*)(&Ct[r][oc4]);
        if (BF16OUT) {
            ushort4 hv;
            hv.x = bf16h(v.x); hv.y = bf16h(v.y); hv.z = bf16h(v.z); hv.w = bf16h(v.w);
            *(ushort4*)((ushort_t*)Cout + (long)(bm + r) * N + bn + oc4) = hv;
        } else {
            *(float4*)((float*)Cout + (long)(bm + r) * N + bn + oc4) = v;
        }
    }
}

// ---------------------------------------------------------------------------
// Attention split, bf16 LDS, triple-buffered, d8 lane layout.
// Block = (scale, row, i-chunk), 192 threads: w = t>>3, hd = (t>>2)&1, d8 = t&3.
// Each thread owns 8 channels; logit dot = ds_read_b128 + 8 FMA + 2 shuffles.
// ---------------------------------------------------------------------------
constexpr int KROW = 72;              // ushort stride per w-position (64 ch + 8 pad)
constexpr int RBUF = WW * KROW;       // 1728 ushorts per buffer

constexpr int EB0 = 0;
constexpr int EB1 = NROW * 2 * WW * 2;         // 18432
constexpr int EB2 = EB1 + NROW * 3 * WW * 2;   // 46080
constexpr int ETOT = EB2 + NROW * 4 * WW * 2;  // 82944

template<int K>
__device__ __forceinline__
void split_chunk(const ushort_t* __restrict__ qkv,
                 float* __restrict__ accs, float* __restrict__ stats,
                 int r, int c, int nchunks, int scale, int ebase,
                 int w, int hd, int d8, int tid,
                 ushort_t* __restrict__ ksh, ushort_t* __restrict__ vsh)
{
    const int i0 = 2 * c;
    const int ni = (K - i0) < 2 ? (K - i0) : 2;
    const int NT = ni * K;

    const int dq = r / HH, hq = r % HH;
    int sd = dq - K / 2; sd = sd < 0 ? 0 : (sd > DD - K ? DD - K : sd);
    int sh = hq - K / 2; sh = sh < 0 ? 0 : (sh > HH - K ? HH - K : sh);
    int sw = w  - K / 2; sw = sw < 0 ? 0 : (sw > WW - K ? WW - K : sw);

    const int q = (dq * HH + hq) * WW + w;

    // q fragment: 8 channels, pre-scaled
    uint4 qu = *(const uint4*)(qkv + (long)q * CQKV + scale * 192 + hd * 32 + d8 * 8);
    float qf[8];
    unpack8(qu, qf);
    #pragma unroll
    for (int t = 0; t < 8; ++t) qf[t] *= ATT_SCALE;

    // staging: thread loads one uint4 (8 bf16 = 16B) of k and of v (pure copy)
    const int lw = tid >> 3;           // 0..23
    const int c8 = (tid & 7) * 8;      // 0..56

    auto load_kv = [&](int buf, int t) {
        int i = i0 + t / K;
        int j = t - (t / K) * K;
        const ushort_t* p = qkv + (long)(((sd + i) * HH + (sh + j)) * WW + lw) * CQKV
                          + scale * 192 + c8;
        uint4 kk = *(const uint4*)(p + 64);
        uint4 vv = *(const uint4*)(p + 128);
        *(uint4*)(ksh + buf * RBUF + lw * KROW + c8) = kk;
        *(uint4*)(vsh + buf * RBUF + lw * KROW + c8) = vv;
    };

    float m = -1e30f, sum = 0.f;
    float acc[8] = {};
    const int choff = hd * 32 + d8 * 8;

    load_kv(0, 0);
    if (NT > 1) load_kv(1, 1);

    for (int t = 0; t < NT; ++t) {
        __syncthreads();
        if (t + 2 < NT) load_kv((t + 2) % 3, t + 2);

        const ushort_t* kb = ksh + (t % 3) * RBUF + choff;
        float lg[K];
        #pragma unroll
        for (int n = 0; n < K; ++n) {
            uint4 ku = *(const uint4*)(kb + (sw + n) * KROW);
            float kf[8];
            unpack8(ku, kf);
            float p = qf[0] * kf[0] + qf[1] * kf[1] + qf[2] * kf[2] + qf[3] * kf[3]
                    + qf[4] * kf[4] + qf[5] * kf[5] + qf[6] * kf[6] + qf[7] * kf[7];
            p += __shfl_xor(p, 1);
            p += __shfl_xor(p, 2);
            lg[n] = p;
        }
        float mloc = lg[0];
        #pragma unroll
        for (int n = 1; n < K; ++n) mloc = fmaxf(mloc, lg[n]);
        float mnew = fmaxf(m, mloc);
        float alpha = __expf(m - mnew);
        m = mnew;
        sum *= alpha;
        #pragma unroll
        for (int d = 0; d < 8; ++d) acc[d] *= alpha;

        const ushort_t* vb = vsh + (t % 3) * RBUF + choff;
        #pragma unroll
        for (int n = 0; n < K; ++n) {
            float pr = __expf(lg[n] - mnew);
            sum += pr;
            uint4 vu = *(const uint4*)(vb + (sw + n) * KROW);
            float vf[8];
            unpack8(vu, vf);
            #pragma unroll
            for (int d = 0; d < 8; ++d) acc[d] += pr * vf[d];
        }
    }

    const int e = ebase + ((r * nchunks + c) * WW + w) * 2 + hd;
    if (d8 == 0) {
        stats[2 * e]     = m;
        stats[2 * e + 1] = sum;
    }
    float* ap = accs + (long)e * 32 + d8 * 8;
    *(float4*)(ap)     = make_float4(acc[0], acc[1], acc[2], acc[3]);
    *(float4*)(ap + 4) = make_float4(acc[4], acc[5], acc[6], acc[7]);
}

__global__ __launch_bounds__(192)
void na3d_split_kernel(const ushort_t* __restrict__ qkv,
                       float* __restrict__ accs, float* __restrict__ stats)
{
    __shared__ alignas(16) ushort_t ksh[3 * RBUF];
    __shared__ alignas(16) ushort_t vsh[3 * RBUF];

    const int tid = threadIdx.x;
    const int w  = tid >> 3;
    const int hd = (tid >> 2) & 1;
    const int d8 = tid & 3;

    const int bid = blockIdx.x;            // 1728 total; longest (K=7) first
    if (bid < NROW * 4) {
        int r = bid >> 2, c = bid & 3;
        split_chunk<7>(qkv, accs, stats, r, c, 4, 2, EB2, w, hd, d8, tid, ksh, vsh);
    } else if (bid < NROW * 4 + NROW * 3) {
        int t = bid - NROW * 4;
        int r = t / 3, c = t - (t / 3) * 3;
        split_chunk<5>(qkv, accs, stats, r, c, 3, 1, EB1, w, hd, d8, tid, ksh, vsh);
    } else {
        int t = bid - NROW * 7;
        int r = t >> 1, c = t & 1;
        split_chunk<3>(qkv, accs, stats, r, c, 2, 0, EB0, w, hd, d8, tid, ksh, vsh);
    }
}

// ---------------------------------------------------------------------------
// Combine: merge CK partials per (q, scale, head); write fp32 y (coalesced).
// one thread per (scale,row,w,hd,d4) = 221184
// ---------------------------------------------------------------------------
__global__ __launch_bounds__(256)
void na3d_combine_kernel(const float* __restrict__ accs,
                         const float* __restrict__ stats,
                         float* __restrict__ y)
{
    const int n = blockIdx.x * 256 + threadIdx.x;
    constexpr int PER_SCALE = NROW * WW * 2 * 8;      // 73728
    const int scale = n / PER_SCALE;
    const int rem = n - scale * PER_SCALE;
    const int d4 = rem & 7;
    const int hd = (rem >> 3) & 1;
    const int t  = rem >> 4;
    const int w  = t % WW;
    const int row = t / WW;

    const int CK = scale == 0 ? 2 : (scale == 1 ? 3 : 4);
    const int ebase = scale == 0 ? EB0 : (scale == 1 ? EB1 : EB2);

    float mv[4], sv[4];
    float M = -1e30f;
    for (int c = 0; c < CK; ++c) {
        int e = ebase + ((row * CK + c) * WW + w) * 2 + hd;
        mv[c] = stats[2 * e];
        sv[c] = stats[2 * e + 1];
        M = fmaxf(M, mv[c]);
    }
    float S = 0.f;
    float4 o = make_float4(0.f, 0.f, 0.f, 0.f);
    for (int c = 0; c < CK; ++c) {
        int e = ebase + ((row * CK + c) * WW + w) * 2 + hd;
        float wgt = __expf(mv[c] - M);
        S += sv[c] * wgt;
        float4 a = *(const float4*)(accs + (long)e * 32 + d4 * 4);
        o.x += wgt * a.x; o.y += wgt * a.y; o.z += wgt * a.z; o.w += wgt * a.w;
    }
    const float rs = 1.0f / S;
    o.x *= rs; o.y *= rs; o.z *= rs; o.w *= rs;

    const int q = row * WW + w;
    *(float4*)(y + (long)q * CIN + scale * 64 + hd * 32 + d4 * 4) = o;
}

// ---------------------------------------------------------------------------
extern "C" void kernel_launch(void* const* d_in, const int* in_sizes, int n_in,
                              void* d_out, int out_size, void* d_ws, size_t ws_size,
                              hipStream_t stream)
{
    const float* x      = (const float*)d_in[0];
    const float* W_qkv  = (const float*)d_in[1];
    const float* b_qkv  = (const float*)d_in[2];
    const float* W_proj = (const float*)d_in[3];
    const float* b_proj = (const float*)d_in[4];
    float* out = (float*)d_out;

    // workspace (~21 MB; ws >= 22.5 MB proven in Round 5)
    float* accs    = (float*)d_ws;                         // ETOT*32 fl
    float* stats   = accs + (long)ETOT * 32;               // 2*ETOT fl
    float* y       = stats + 2 * ETOT;                     // NQ*192 fl
    ushort_t* qkvb = (ushort_t*)(y + (long)NQ * CIN);      // NQ*576 us
    ushort_t* Wbq  = qkvb + (long)NQ * CQKV;               // 576*576 us
    ushort_t* Wbp  = Wbq + (long)CQKV * KP;                // 192*576 us

    // 1) weight conversion (one dispatch, both weights)
    convert_w_kernel<<<dim3(144), 256, 0, stream>>>(W_qkv, W_proj, Wbq, Wbp);

    // 2) qkv = x @ W_qkv + b_qkv  (fp32 A consumed directly) -> bf16
    gemm_mfma_kernel<true><<<dim3(NQ / 64, CQKV / 64), 256, 0, stream>>>(x, Wbq, b_qkv, qkvb, CQKV);

    // 3) attention split + combine -> fp32 y
    na3d_split_kernel<<<dim3(NROW * (4 + 3 + 2)), 192, 0, stream>>>(qkvb, accs, stats);
    na3d_combine_kernel<<<dim3(3 * NQ * 16 / 256), 256, 0, stream>>>(accs, stats, y);

    // 4) out = y @ W_proj + b_proj  (fp32 A consumed directly) -> fp32
    gemm_mfma_kernel<false><<<dim3(NQ / 64, CIN / 64), 256, 0, stream>>>(y, Wbp, b_proj, out, CIN);
}